// Round 19
// baseline (470.406 us; speedup 1.0000x reference)
//
#include <hip/hip_runtime.h>
#include <math.h>

#define N_DST   32768
#define N_EDGE  524288
#define LN_EPS  1e-5f

// ---------- prep: zq, Wv transpose, wout transpose ----------
// Wvt[cc][o] = wkv_w[100+o][cc]  (V weights, [300][100])
// wout_t[i][o] = wout_w[o][i]    ([200][100])
__global__ void k_prep(const float* __restrict__ wkv_w, const float* __restrict__ wq_w,
                       const float* __restrict__ wq_b, const float* __restrict__ time_b,
                       const float* __restrict__ wout_w,
                       float* __restrict__ zq, float* __restrict__ Wvt,
                       float* __restrict__ wout_t) {
    int idx = blockIdx.x * 256 + threadIdx.x;
    if (idx < 100) {
        float acc = wq_b[idx];
        for (int j = 0; j < 100; ++j)
            acc += cosf(time_b[j]) * wq_w[idx * 200 + 100 + j];
        zq[idx] = acc;
    } else if (idx < 30100) {
        int r = idx - 100, cc = r / 100, o = r % 100;
        Wvt[r] = wkv_w[(size_t)(100 + o) * 300 + cc];
    } else if (idx < 50100) {
        int r = idx - 30100;
        wout_t[r] = wout_w[(size_t)(r % 100) * 200 + r / 100];
    }
}

// ---------- A2[i][j], C2[j]: fold Q-projection into QW map (j<600: X-dims; j=600+h: K-bias dot) ----------
// QW[n][j] = sum_i dst_h[n][i]*A2[i][j] + C2[j]
// j = h*300+cc: QW = sum_d Q[n][h*50+d]*wkv_w[h*50+d][cc];  j=600+h: B(n,h)=sum_d Q*wkv_b
__global__ void k_precomp(const float* __restrict__ wq_w, const float* __restrict__ wkv_w,
                          const float* __restrict__ wkv_b, const float* __restrict__ zq,
                          float* __restrict__ A2, float* __restrict__ C2) {
    int idx = blockIdx.x * 256 + threadIdx.x;
    if (idx < 60200) {
        int i = idx / 602, j = idx % 602;
        float acc = 0.f;
        if (j < 600) {
            int h = j / 300, cc = j % 300;
            const float* __restrict__ wq = wq_w + (size_t)(h * 50) * 200 + i;
            const float* __restrict__ wk = wkv_w + (size_t)(h * 50) * 300 + cc;
            #pragma unroll 10
            for (int d = 0; d < 50; ++d)
                acc = fmaf(wq[(size_t)d * 200], wk[(size_t)d * 300], acc);
        } else {
            int h = j - 600;
            const float* __restrict__ wq = wq_w + (size_t)(h * 50) * 200 + i;
            for (int d = 0; d < 50; ++d)
                acc = fmaf(wq[(size_t)d * 200], wkv_b[h * 50 + d], acc);
        }
        A2[idx] = acc;
    } else if (idx < 60802) {
        int j = idx - 60200;
        float acc = 0.f;
        if (j < 600) {
            int h = j / 300, cc = j % 300;
            for (int d = 0; d < 50; ++d)
                acc = fmaf(zq[h * 50 + d], wkv_w[(size_t)(h * 50 + d) * 300 + cc], acc);
        } else {
            int h = j - 600;
            for (int d = 0; d < 50; ++d)
                acc = fmaf(zq[h * 50 + d], wkv_b[h * 50 + d], acc);
        }
        C2[j] = acc;
    }
}

// ---------- CSR offsets via binary search over sorted edge_dst ----------
__global__ void k_offsets(const int* __restrict__ dst, int* __restrict__ off) {
    int n = blockIdx.x * 256 + threadIdx.x;
    if (n > N_DST) return;
    int lo = 0, hi = N_EDGE;
    while (lo < hi) {
        int mid = (lo + hi) >> 1;
        if (dst[mid] < n) lo = mid + 1; else hi = mid;
    }
    off[n] = lo;
}

// ---------- QW[n][0..601] = dst_h[n] @ A2 + C2 : 32 nodes/block (row stride 608) ----------
__global__ __launch_bounds__(256) void k_qw(const float* __restrict__ dst_h,
                                            const float* __restrict__ A2,
                                            const float* __restrict__ C2,
                                            float* __restrict__ QW) {
    __shared__ float Ds[32][100];
    int n0 = blockIdx.x * 32, t = threadIdx.x;
    for (int idx = t; idx < 3200; idx += 256)
        Ds[idx / 100][idx % 100] = dst_h[(size_t)n0 * 100 + idx];
    __syncthreads();
    for (int pass = 0; pass < 3; ++pass) {
        int c = pass * 256 + t;
        if (c >= 602) break;
        float cb = C2[c];
        float acc[32];
        #pragma unroll
        for (int n = 0; n < 32; ++n) acc[n] = cb;
        for (int k = 0; k < 100; ++k) {
            float a = A2[(size_t)k * 602 + c];
            #pragma unroll
            for (int n = 0; n < 32; ++n) acc[n] = fmaf(Ds[n][k], a, acc[n]);
        }
        #pragma unroll
        for (int n = 0; n < 32; ++n) QW[(size_t)(n0 + n) * 608 + c] = acc[n];
    }
}

// ---------- k_node: streaming flash-style edge pass. ONE wave per node. ----------
// logit_e = X_e . QW[n] + B(n,h) -> leaky -> online softmax -> Xagg[n] = sum a_e X_e.
// Lane layout over cc in [0,300): slot s holds cc = s*64+lane (s=4 valid lane<44).
__global__ __launch_bounds__(256) void k_node(
        const float* __restrict__ src_h, const float* __restrict__ efeat,
        const float* __restrict__ td,
        const float* __restrict__ time_w, const float* __restrict__ time_b,
        const float* __restrict__ QW, const int* __restrict__ off,
        float* __restrict__ Xagg) {
    const int lane = threadIdx.x & 63;
    const int n = blockIdx.x * 4 + (threadIdx.x >> 6);
    const int r0 = off[n], cnt = off[n + 1] - r0;
    float* __restrict__ xo = Xagg + (size_t)n * 600;
    if (cnt <= 0) {
        #pragma unroll
        for (int s = 0; s < 5; ++s) {
            int cc = s * 64 + lane;
            if (cc < 300) { xo[cc] = 0.f; xo[300 + cc] = 0.f; }
        }
        return;
    }
    // per-lane constants
    float qw0[5], qw1[5];
    #pragma unroll
    for (int s = 0; s < 5; ++s) {
        int cc = s * 64 + lane;
        qw0[s] = (cc < 300) ? QW[(size_t)n * 608 + cc]       : 0.f;
        qw1[s] = (cc < 300) ? QW[(size_t)n * 608 + 300 + cc] : 0.f;
    }
    const float B0 = QW[(size_t)n * 608 + 600];
    const float B1 = QW[(size_t)n * 608 + 601];
    float tw3 = 0.f, tb3 = 0.f, tw4 = 0.f, tb4 = 0.f;
    if (lane >= 8) { tw3 = time_w[lane - 8]; tb3 = time_b[lane - 8]; }     // cc=192+lane
    if (lane < 44) { tw4 = time_w[56 + lane]; tb4 = time_b[56 + lane]; }   // cc=256+lane

    auto LOADX = [&](float* x, int r) {
        const float* __restrict__ sr = src_h + (size_t)r * 100;
        const float* __restrict__ er = efeat + (size_t)r * 100;
        const float tdv = td[r];
        x[0] = sr[lane];
        x[1] = (lane < 36) ? sr[64 + lane] : er[lane - 36];
        x[2] = er[28 + lane];
        x[3] = (lane < 8) ? er[92 + lane] : __cosf(fmaf(tdv, tw3, tb3));
        x[4] = (lane < 44) ? __cosf(fmaf(tdv, tw4, tb4)) : 0.f;
    };

    float m0 = -1e30f, m1 = -1e30f, sum0 = 0.f, sum1 = 0.f;
    float a0[5] = {0.f, 0.f, 0.f, 0.f, 0.f}, a1[5] = {0.f, 0.f, 0.f, 0.f, 0.f};
    float xA[5], xB[5];
    LOADX(xA, r0);
    for (int i = 0; i < cnt; ++i) {
        if (i + 1 < cnt) LOADX(xB, r0 + i + 1);      // prefetch next edge row
        float p0 = 0.f, p1 = 0.f;
        #pragma unroll
        for (int s = 0; s < 5; ++s) {
            p0 = fmaf(xA[s], qw0[s], p0);
            p1 = fmaf(xA[s], qw1[s], p1);
        }
        #pragma unroll
        for (int sh = 1; sh < 64; sh <<= 1) {
            p0 += __shfl_xor(p0, sh);
            p1 += __shfl_xor(p1, sh);
        }
        float l0 = p0 + B0; l0 = l0 > 0.f ? l0 : 0.2f * l0;
        float l1 = p1 + B1; l1 = l1 > 0.f ? l1 : 0.2f * l1;
        float m0n = fmaxf(m0, l0), m1n = fmaxf(m1, l1);
        float r0f = __expf(m0 - m0n), r1f = __expf(m1 - m1n);
        float w0 = __expf(l0 - m0n),  w1 = __expf(l1 - m1n);
        sum0 = fmaf(sum0, r0f, w0);
        sum1 = fmaf(sum1, r1f, w1);
        #pragma unroll
        for (int s = 0; s < 5; ++s) {
            a0[s] = fmaf(a0[s], r0f, w0 * xA[s]);
            a1[s] = fmaf(a1[s], r1f, w1 * xA[s]);
        }
        m0 = m0n; m1 = m1n;
        if (i + 1 < cnt) {
            #pragma unroll
            for (int s = 0; s < 5; ++s) xA[s] = xB[s];
        }
    }
    const float inv0 = 1.f / sum0, inv1 = 1.f / sum1;
    #pragma unroll
    for (int s = 0; s < 5; ++s) {
        int cc = s * 64 + lane;
        if (cc < 300) {
            xo[cc]       = a0[s] * inv0;
            xo[300 + cc] = a1[s] * inv1;
        }
    }
}

// ---------- k_aggv: agg[n][o] = Xagg[n][h(o)] . Wvt[:,o] + b_v[o]*(cnt>0) ----------
__global__ __launch_bounds__(128) void k_aggv(const float* __restrict__ Xagg,
                                              const float* __restrict__ Wvt,
                                              const float* __restrict__ wkv_b,
                                              const int* __restrict__ off,
                                              float* __restrict__ agg) {
    __shared__ float Xs[8][600];
    const int n0 = blockIdx.x * 8, t = threadIdx.x;
    for (int idx = t; idx < 4800; idx += 128)
        Xs[idx / 600][idx % 600] = Xagg[(size_t)n0 * 600 + idx];
    __syncthreads();
    if (t < 100) {
        const int hb = (t / 50) * 300;
        float acc[8];
        #pragma unroll
        for (int n = 0; n < 8; ++n)
            acc[n] = (off[n0 + n + 1] > off[n0 + n]) ? wkv_b[100 + t] : 0.f;
        for (int cc = 0; cc < 300; ++cc) {
            float w = Wvt[cc * 100 + t];
            #pragma unroll
            for (int n = 0; n < 8; ++n) acc[n] = fmaf(Xs[n][hb + cc], w, acc[n]);
        }
        #pragma unroll
        for (int n = 0; n < 8; ++n) agg[(size_t)(n0 + n) * 100 + t] = acc[n];
    }
}

// ---------- out proj + relu + layernorm: 8 nodes/block, coalesced wout_t ----------
__global__ __launch_bounds__(128) void k_out(const float* __restrict__ agg,
                                             const float* __restrict__ dst_h,
                                             const float* __restrict__ wout_t,
                                             const float* __restrict__ wout_b,
                                             const float* __restrict__ ln_g,
                                             const float* __restrict__ ln_b,
                                             float* __restrict__ out) {
    __shared__ float Fs[8][200];
    __shared__ float red[8][128];
    const int n0 = blockIdx.x * 8, t = threadIdx.x;
    for (int idx = t; idx < 1600; idx += 128) {
        int n = idx / 200, i = idx % 200;
        Fs[n][i] = (i < 100) ? agg[(size_t)(n0 + n) * 100 + i]
                             : dst_h[(size_t)(n0 + n) * 100 + (i - 100)];
    }
    __syncthreads();
    float v[8] = {0.f, 0.f, 0.f, 0.f, 0.f, 0.f, 0.f, 0.f};
    if (t < 100) {
        float b = wout_b[t];
        #pragma unroll
        for (int n = 0; n < 8; ++n) v[n] = b;
        for (int i = 0; i < 200; ++i) {
            float w = wout_t[i * 100 + t];
            #pragma unroll
            for (int n = 0; n < 8; ++n) v[n] = fmaf(Fs[n][i], w, v[n]);
        }
        #pragma unroll
        for (int n = 0; n < 8; ++n) v[n] = fmaxf(v[n], 0.f);
    }
    #pragma unroll
    for (int n = 0; n < 8; ++n) red[n][t] = (t < 100) ? v[n] : 0.f;
    __syncthreads();
    for (int s = 64; s > 0; s >>= 1) {
        if (t < s) {
            #pragma unroll
            for (int n = 0; n < 8; ++n) red[n][t] += red[n][t + s];
        }
        __syncthreads();
    }
    float mu[8];
    #pragma unroll
    for (int n = 0; n < 8; ++n) mu[n] = red[n][0] * 0.01f;
    __syncthreads();
    #pragma unroll
    for (int n = 0; n < 8; ++n) {
        float dv = (t < 100) ? (v[n] - mu[n]) : 0.f;
        red[n][t] = dv * dv;
    }
    __syncthreads();
    for (int s = 64; s > 0; s >>= 1) {
        if (t < s) {
            #pragma unroll
            for (int n = 0; n < 8; ++n) red[n][t] += red[n][t + s];
        }
        __syncthreads();
    }
    if (t < 100) {
        #pragma unroll
        for (int n = 0; n < 8; ++n) {
            float var = red[n][0] * 0.01f;
            out[(size_t)(n0 + n) * 100 + t] =
                (v[n] - mu[n]) * rsqrtf(var + LN_EPS) * ln_g[t] + ln_b[t];
        }
    }
}

extern "C" void kernel_launch(void* const* d_in, const int* in_sizes, int n_in,
                              void* d_out, int out_size, void* d_ws, size_t ws_size,
                              hipStream_t stream) {
    const float* dst_h   = (const float*)d_in[0];
    const float* src_h   = (const float*)d_in[1];
    const float* efeat   = (const float*)d_in[2];
    const float* td      = (const float*)d_in[3];
    const int*   edst    = (const int*)  d_in[4];
    const float* time_w  = (const float*)d_in[5];
    const float* time_b  = (const float*)d_in[6];
    const float* wq_w    = (const float*)d_in[7];
    const float* wq_b    = (const float*)d_in[8];
    const float* wkv_w   = (const float*)d_in[9];
    const float* wkv_b   = (const float*)d_in[10];
    const float* wout_w  = (const float*)d_in[11];
    const float* wout_b  = (const float*)d_in[12];
    const float* ln_g    = (const float*)d_in[13];
    const float* ln_b    = (const float*)d_in[14];
    float* out = (float*)d_out;

    char* ws = (char*)d_ws;
    size_t off = 0;
    auto carve = [&](size_t bytes) { char* p = ws + off; off = (off + bytes + 255) & ~(size_t)255; return p; };
    float* QW    = (float*)carve((size_t)N_DST * 608 * 4);
    float* Xagg  = (float*)carve((size_t)N_DST * 600 * 4);
    float* agg   = (float*)carve((size_t)N_DST * 100 * 4);
    float* A2    = (float*)carve(60200 * 4);
    float* C2    = (float*)carve(602 * 4);
    float* Wvt   = (float*)carve(30000 * 4);
    float* woutT = (float*)carve(20000 * 4);
    float* zq    = (float*)carve(100 * 4);
    int*   offs  = (int*)carve((size_t)(N_DST + 1) * 4);

    k_prep<<<(50100 + 255) / 256, 256, 0, stream>>>(wkv_w, wq_w, wq_b, time_b, wout_w,
                                                    zq, Wvt, woutT);
    k_precomp<<<(60802 + 255) / 256, 256, 0, stream>>>(wq_w, wkv_w, wkv_b, zq, A2, C2);
    k_offsets<<<(N_DST + 1 + 255) / 256, 256, 0, stream>>>(edst, offs);
    k_qw<<<N_DST / 32, 256, 0, stream>>>(dst_h, A2, C2, QW);
    k_node<<<N_DST / 4, 256, 0, stream>>>(src_h, efeat, td, time_w, time_b,
                                          QW, offs, Xagg);
    k_aggv<<<N_DST / 8, 128, 0, stream>>>(Xagg, Wvt, wkv_b, offs, agg);
    k_out<<<N_DST / 8, 128, 0, stream>>>(agg, dst_h, woutT, wout_b, ln_g, ln_b, out);
}